// Round 5
// baseline (75.146 us; speedup 1.0000x reference)
//
#include <hip/hip_runtime.h>
#include <hip/hip_bf16.h>

#define NCH 64
#define NEL 10
// Basis: 172 cubic chunks (72 full-pair j<=7, 100 h1-only j>=8) + 20 tail chunks = 192 chunks
// = 48 MFMA K-steps of 32. Table layout: W[ec][o][chunk-unit u][8 j] bf16, where the
// 16B chunk n of row o is stored at unit u = n ^ (o&7)  (XOR swizzle so k_main's
// LDS ds_read_b128 across o-rows is 2-way bank-conflict-free; producer-side baked).
#define NCHUNK 192
#define NSTEP 48

#define WS_OFFS  0
#define WS_LIST  1024
#define WS_W     8192        // 640 * 16 * 192 * 8 * 2B = 31.46 MB

typedef __attribute__((ext_vector_type(8))) short  short8v;
typedef __attribute__((ext_vector_type(4))) float  float4v;
typedef __attribute__((ext_vector_type(4))) int    int4v;

// pair enumerations:
// full region (j<=7): for j in 0..7: for i in 0..j   (36 pairs)
__host__ __device__ constexpr int PJF(int p) { int j = 0; while (p >= j + 1) { p -= j + 1; ++j; } return j; }
__host__ __device__ constexpr int PIF(int p) { int j = 0; while (p >= j + 1) { p -= j + 1; ++j; } return p; }
// h1 region (j>=8): for j in 8..15: for i in 0..j    (100 pairs)
__host__ __device__ constexpr int PJH(int p) { int j = 8; while (p >= j + 1) { p -= j + 1; ++j; } return j; }
__host__ __device__ constexpr int PIH(int p) { int j = 8; while (p >= j + 1) { p -= j + 1; ++j; } return p; }

__device__ __forceinline__ unsigned short f_to_bf16u(float f) {
  union { float f; unsigned int i; } v; v.f = f;
  unsigned int x = v.i;
  unsigned int r = (x + 0x7fffu + ((x >> 16) & 1u)) >> 16;
  return (unsigned short)r;
}

// ---------------- kernel 0: bucket nodes by element ----------------
__global__ void k_lists(const int* __restrict__ idx, int* __restrict__ ws_offs,
                        int* __restrict__ ws_list) {
  __shared__ int cnt[NEL];
  __shared__ int base[NEL + 1];
  int t = threadIdx.x;
  if (t < NEL) cnt[t] = 0;
  __syncthreads();
  int e = idx[t];
  int pos = atomicAdd(&cnt[e], 1);
  __syncthreads();
  if (t == 0) {
    int a = 0;
    for (int i = 0; i < NEL; ++i) { base[i] = a; a += cnt[i]; }
    base[NEL] = a;
  }
  __syncthreads();
  ws_list[base[e] + pos] = t;
  if (t <= NEL) ws_offs[t] = base[t];
}

// ---------------- kernel 1: build W (bf16, producer-swizzled) ----------------
// grid = (o*10+e)*8 + (c&7). 192 threads, thread = chunk n.
// v3: channel loop split in 2 halves of 4; weight columns preloaded from LDS
// into 64 VGPRs per half -> hot loop is pure register FMA (no LDS reads, no
// 64-reg acc + preload co-residency -> no spill).
__global__ __launch_bounds__(192, 3) void k_build(const float* __restrict__ U3,
                                                  const float* __restrict__ U2,
                                                  const float* __restrict__ U1,
                                                  const float* __restrict__ w3,
                                                  const float* __restrict__ w2,
                                                  const float* __restrict__ w1,
                                                  unsigned short* __restrict__ W) {
  int blk = blockIdx.x;
  int x7 = blk & 7;
  int oe = blk >> 3;
  int e = oe % 10;
  int o = oe / 10;
  int n = threadIdx.x;                 // chunk id 0..191

  __shared__ float sw3[16 * 8];        // [k][m], c = x7 + 8*m
  __shared__ float sw2[8 * 8];
  __shared__ float sw1[4 * 8];
  if (n < 128) { int k = n >> 3, m = n & 7; sw3[n] = w3[(e * 16 + k) * NCH + x7 + 8 * m]; }
  else { int q = n - 128; if (q < 64) { int k = q >> 3, m = q & 7; sw2[q] = w2[(e * 8 + k) * NCH + x7 + 8 * m]; } }
  if (n < 32) { int k = n >> 3, m = n & 7; sw1[n] = w1[(e * 4 + k) * NCH + x7 + 8 * m]; }
  __syncthreads();

  int ci = 0, cj = 0, h = 1, type;     // type 0 = cubic, 1 = tail
  int r0 = 0;
  if (n < 72) {                        // full-pair region
    int p = n >> 1; h = n & 1;
    int j = 0; while (p >= j + 1) { p -= j + 1; ++j; }
    ci = p; cj = j; type = 0;
  } else if (n < 172) {                // h1 region
    int p = n - 72; h = 1;
    int j = 8; while (p >= j + 1) { p -= j + 1; ++j; }
    ci = p; cj = j; type = 0;
  } else {
    r0 = (n - 172) * 8; type = 1;
  }
  int ustore = n ^ (o & 7);            // producer-side XOR swizzle (uniform o)

#pragma unroll 1
  for (int h2 = 0; h2 < 2; ++h2) {
    float acc[4][8];                   // [mm][jj] — static indexing only
#pragma unroll
    for (int mm = 0; mm < 4; ++mm)
#pragma unroll
      for (int jj = 0; jj < 8; ++jj) acc[mm][jj] = 0.f;

    if (type == 0) {
      float swv[16][4];                // swv[k][mm] = sw3[k][h2*4+mm]
#pragma unroll
      for (int k = 0; k < 16; ++k) {
        float4 q = *(const float4*)&sw3[k * 8 + h2 * 4];
        swv[k][0] = q.x; swv[k][1] = q.y; swv[k][2] = q.z; swv[k][3] = q.w;
      }
#pragma unroll
      for (int jj = 0; jj < 8; ++jj) {
        int l = h * 8 + jj;
        if (l >= cj) {                 // canonical i<=j<=l
          const float4* lp = (const float4*)(U3 + ((((size_t)o * 16 + ci) * 16 + cj) * 16 + l) * 16);
          float4 q0 = lp[0], q1 = lp[1], q2 = lp[2], q3 = lp[3];
          float line[16] = {q0.x, q0.y, q0.z, q0.w, q1.x, q1.y, q1.z, q1.w,
                            q2.x, q2.y, q2.z, q2.w, q3.x, q3.y, q3.z, q3.w};
          float mult = (ci == cj) ? (cj == l ? 1.f : 3.f) : (cj == l ? 3.f : 6.f);
#pragma unroll
          for (int k = 0; k < 16; ++k) {
            float lk = line[k] * mult;
#pragma unroll
            for (int mm = 0; mm < 4; ++mm) acc[mm][jj] += lk * swv[k][mm];
          }
        }
      }
    } else {
      float swv2[8][4], swv1[4][4];
#pragma unroll
      for (int k = 0; k < 8; ++k) {
        float4 q = *(const float4*)&sw2[k * 8 + h2 * 4];
        swv2[k][0] = q.x; swv2[k][1] = q.y; swv2[k][2] = q.z; swv2[k][3] = q.w;
      }
#pragma unroll
      for (int k = 0; k < 4; ++k) {
        float4 q = *(const float4*)&sw1[k * 8 + h2 * 4];
        swv1[k][0] = q.x; swv1[k][1] = q.y; swv1[k][2] = q.z; swv1[k][3] = q.w;
      }
#pragma unroll
      for (int jj = 0; jj < 8; ++jj) {
        int r = r0 + jj;
        if (r < 136) {                 // quad pairs, i-major (matches k_main sT)
          int p = r, i2 = 0; while (p >= 16 - i2) { p -= 16 - i2; ++i2; }
          int a = i2, b = i2 + p;
          const float4* lp = (const float4*)(U2 + (((o * 16 + a) * 16) + b) * 8);
          float4 q0 = lp[0], q1 = lp[1];
          float line[8] = {q0.x, q0.y, q0.z, q0.w, q1.x, q1.y, q1.z, q1.w};
          float sc = (a == b) ? 1.f : 2.f;
#pragma unroll
          for (int k = 0; k < 8; ++k) {
            float lk = line[k] * sc;
#pragma unroll
            for (int mm = 0; mm < 4; ++mm) acc[mm][jj] += lk * swv2[k][mm];
          }
        } else if (r < 152) {          // linear
          int a = r - 136;
          float4 q0 = *(const float4*)(U1 + (o * 16 + a) * 4);
          float line[4] = {q0.x, q0.y, q0.z, q0.w};
#pragma unroll
          for (int k = 0; k < 4; ++k) {
#pragma unroll
            for (int mm = 0; mm < 4; ++mm) acc[mm][jj] += line[k] * swv1[k][mm];
          }
        }
      }
    }

#pragma unroll
    for (int mm = 0; mm < 4; ++mm) {
      int c = x7 + 8 * (h2 * 4 + mm);
      int ec = e * 64 + c;
      uint4 st;
      st.x = (unsigned)f_to_bf16u(acc[mm][0]) | ((unsigned)f_to_bf16u(acc[mm][1]) << 16);
      st.y = (unsigned)f_to_bf16u(acc[mm][2]) | ((unsigned)f_to_bf16u(acc[mm][3]) << 16);
      st.z = (unsigned)f_to_bf16u(acc[mm][4]) | ((unsigned)f_to_bf16u(acc[mm][5]) << 16);
      st.w = (unsigned)f_to_bf16u(acc[mm][6]) | ((unsigned)f_to_bf16u(acc[mm][7]) << 16);
      *(uint4*)(W + (((size_t)ec * 16 + o) * NCHUNK + ustore) * 8) = st;
    }
  }
}

// ---------------- kernel 2: MFMA main (W staged in LDS once per block) ----------------
#define PACK_MFMA(M0, M1, M2, M3, M4, M5, M6, M7, KK, ACC) { \
  int b0, b1, b2, b3; \
  asm("v_cvt_pk_bf16_f32 %0, %1, %2" : "=v"(b0) : "v"(M0), "v"(M1)); \
  asm("v_cvt_pk_bf16_f32 %0, %1, %2" : "=v"(b1) : "v"(M2), "v"(M3)); \
  asm("v_cvt_pk_bf16_f32 %0, %1, %2" : "=v"(b2) : "v"(M4), "v"(M5)); \
  asm("v_cvt_pk_bf16_f32 %0, %1, %2" : "=v"(b3) : "v"(M6), "v"(M7)); \
  int4v ai = {b0, b1, b2, b3}; \
  short8v av = __builtin_bit_cast(short8v, ai); \
  short8v bv = *(const short8v*)(((KK) & 1 ? bpO : bpE) + ((KK) >> 1) * 128); \
  ACC = __builtin_amdgcn_mfma_f32_16x16x32_bf16(av, bv, ACC, 0, 0, 0); \
}

#define FULL_STEP(KK, ACC) { \
  constexpr int iA = PIF(2 * (KK)), jA = PJF(2 * (KK)); \
  constexpr int iB = PIF(2 * (KK) + 1), jB = PJF(2 * (KK) + 1); \
  float xxA = xr[iA] * xr[jA]; \
  float xxB = xr[iB] * xr[jB]; \
  float xx = selOdd ? xxB : xxA; \
  PACK_MFMA(xx * xsF[0], xx * xsF[1], xx * xsF[2], xx * xsF[3], \
            xx * xsF[4], xx * xsF[5], xx * xsF[6], xx * xsF[7], KK, ACC) \
}

#define H1_STEP(KK, ACC) { \
  constexpr int q = 4 * ((KK) - 18); \
  constexpr int i0 = PIH(q), j0 = PJH(q); \
  constexpr int i1 = PIH(q + 1), j1 = PJH(q + 1); \
  constexpr int i2 = PIH(q + 2), j2 = PJH(q + 2); \
  constexpr int i3 = PIH(q + 3), j3 = PJH(q + 3); \
  float xx0 = xr[i0] * xr[j0], xx1 = xr[i1] * xr[j1]; \
  float xx2 = xr[i2] * xr[j2], xx3 = xr[i3] * xr[j3]; \
  float xxE = selG1 ? xx1 : xx0; \
  float xxO = selG1 ? xx3 : xx2; \
  float xx = selOdd ? xxO : xxE; \
  PACK_MFMA(xx * xr[8], xx * xr[9], xx * xr[10], xx * xr[11], \
            xx * xr[12], xx * xr[13], xx * xr[14], xx * xr[15], KK, ACC) \
}

#define TAIL_STEP(KK, ACC) { \
  float mv[8]; \
  _Pragma("unroll") \
  for (int jj = 0; jj < 8; ++jj) { \
    int spec = sT[((KK) - 43) * 32 + g * 8 + jj]; \
    mv[jj] = sXw[spec & 31] * sXw[(spec >> 8) & 31]; \
  } \
  PACK_MFMA(mv[0], mv[1], mv[2], mv[3], mv[4], mv[5], mv[6], mv[7], KK, ACC) \
}

__global__ __launch_bounds__(512, 4) void k_main(const float* __restrict__ x,
                                                 const int* __restrict__ offs,
                                                 const int* __restrict__ list,
                                                 const unsigned short* __restrict__ W,
                                                 float* __restrict__ out) {
  __shared__ unsigned short sB[16 * NCHUNK * 8];   // 49152 B, producer-swizzled W[ec]
  __shared__ float sX[8][16][18];
  __shared__ int sT[160];
  int t = threadIdx.x;
  int w = t >> 6, lane = t & 63;
  int rc = lane & 15;
  int g = lane >> 4;
  bool selOdd = g >= 2;
  bool selG1 = g & 1;

  int ec = blockIdx.x;                 // block b -> XCD b%8 == ec%8 (matches k_build home)
  int e = ec >> 6, c = ec & 63;

  // stage W[ec] -> LDS (reg-staged, linear; swizzle already baked by producer)
  {
    const uint4* Wg4 = (const uint4*)(W + (size_t)ec * (16 * NCHUNK * 8));
    uint4* sB4 = (uint4*)sB;
#pragma unroll
    for (int s = 0; s < 6; ++s) sB4[t + 512 * s] = Wg4[t + 512 * s];
  }
  if (t < 160) {
    int r = t, a, b;
    if (r < 136) { int p = r, i2 = 0; while (p >= 16 - i2) { p -= 16 - i2; ++i2; } a = i2; b = i2 + p; }
    else if (r < 152) { a = r - 136; b = 16; }
    else { a = 17; b = 17; }
    sT[r] = a | (b << 8);
  }
  __syncthreads();

  float* sXw = &sX[w][rc][0];
  int off = offs[e], nb = offs[e + 1] - off;
  int nt = (nb + 15) >> 4;
  // swizzled per-lane B bases: unit = rc*192 + (KK>>1)*8 + 4*((KK&1)^r2) + (g^(rc&3))
  int r2 = (rc >> 2) & 1;
  const char* bpE = (const char*)sB + rc * 3072 + ((g ^ (rc & 3)) + 4 * r2) * 16;
  const char* bpO = (const char*)sB + rc * 3072 + ((g ^ (rc & 3)) + 4 * (1 ^ r2)) * 16;

  for (int tile = w; tile < nt; tile += 8) {
    int m = tile * 16 + rc;
    int node = list[off + (m < nb ? m : nb - 1)];
    float xr[16];
    {
      const float4* xp = (const float4*)(x + ((size_t)node * NCH + c) * 16);
      float4 q0 = xp[0], q1 = xp[1], q2 = xp[2], q3 = xp[3];
      xr[0] = q0.x; xr[1] = q0.y; xr[2] = q0.z; xr[3] = q0.w;
      xr[4] = q1.x; xr[5] = q1.y; xr[6] = q1.z; xr[7] = q1.w;
      xr[8] = q2.x; xr[9] = q2.y; xr[10] = q2.z; xr[11] = q2.w;
      xr[12] = q3.x; xr[13] = q3.y; xr[14] = q3.z; xr[15] = q3.w;
    }
    float xsF[8];
#pragma unroll
    for (int j = 0; j < 8; ++j) xsF[j] = selG1 ? xr[8 + j] : xr[j];
    if (g == 0) {                      // publish row for tail steps (same-wave use only)
#pragma unroll
      for (int l = 0; l < 16; ++l) sXw[l] = xr[l];
      sXw[16] = 1.f; sXw[17] = 0.f;
    }

    float4v acc0 = {0.f, 0.f, 0.f, 0.f};
    float4v acc1 = {0.f, 0.f, 0.f, 0.f};
#define S2F(K) FULL_STEP(K, acc0) FULL_STEP((K) + 1, acc1)
#define S2H(K) H1_STEP(K, acc0) H1_STEP((K) + 1, acc1)
    S2F(0) S2F(2) S2F(4) S2F(6) S2F(8) S2F(10) S2F(12) S2F(14) S2F(16)
    S2H(18) S2H(20) S2H(22) S2H(24) S2H(26) S2H(28) S2H(30) S2H(32)
    S2H(34) S2H(36) S2H(38) S2H(40)
    H1_STEP(42, acc0)
    TAIL_STEP(43, acc1)
    TAIL_STEP(44, acc0) TAIL_STEP(45, acc1)
    TAIL_STEP(46, acc0) TAIL_STEP(47, acc1)
    float4v accs = acc0 + acc1;

#pragma unroll
    for (int r3 = 0; r3 < 4; ++r3) {
      int row = g * 4 + r3;
      int mrow = tile * 16 + row;
      if (mrow < nb) {
        int nd = __shfl(node, row);
        out[((size_t)nd * NCH + c) * 16 + rc] = accs[r3];
      }
    }
  }
}

extern "C" void kernel_launch(void* const* d_in, const int* in_sizes, int n_in,
                              void* d_out, int out_size, void* d_ws, size_t ws_size,
                              hipStream_t stream) {
  (void)in_sizes; (void)n_in; (void)out_size; (void)ws_size;
  const float* x   = (const float*)d_in[0];
  const int*   idx = (const int*)d_in[1];
  const float* w1  = (const float*)d_in[2];
  const float* w2  = (const float*)d_in[3];
  const float* w3  = (const float*)d_in[4];
  const float* U1  = (const float*)d_in[5];
  const float* U2  = (const float*)d_in[6];
  const float* U3  = (const float*)d_in[7];
  float* out = (float*)d_out;
  char* ws = (char*)d_ws;
  int* ws_offs = (int*)(ws + WS_OFFS);
  int* ws_list = (int*)(ws + WS_LIST);
  unsigned short* W = (unsigned short*)(ws + WS_W);

  hipLaunchKernelGGL(k_lists, dim3(1), dim3(1024), 0, stream, idx, ws_offs, ws_list);
  hipLaunchKernelGGL(k_build, dim3(1280), dim3(192), 0, stream, U3, U2, U1, w3, w2, w1, W);
  hipLaunchKernelGGL(k_main, dim3(640), dim3(512), 0, stream, x, ws_offs, ws_list, W, out);
}

// Round 6
// 53.485 us; speedup vs baseline: 1.4050x; 1.4050x over previous
//
#include <hip/hip_runtime.h>
#include <hip/hip_bf16.h>

#define NCH 64
#define NEL 10
// Basis: 172 cubic chunks (72 full-pair j<=7, 100 h1-only j>=8) + 20 tail chunks = 192 chunks
// = 48 MFMA K-steps of 32. Table layout: W[ec][o][chunk-unit u][8 j] bf16, where the
// 16B chunk n of row o is stored at unit u = n ^ (o&7)  (XOR swizzle, baked at build).
#define NCHUNK 192
#define NSTEP 48
#define NROWS 24576          // 16 o * 192 units * 8 jj  (= per-ec W row count)

#define WS_OFFS   0
#define WS_LIST   1024
#define WS_WALLT  8192       // 640 * 32 * 2B = 40960
#define WS_UPACK  65536      // 24576 * 32 * 2B = 1572864
#define WS_W      2097152    // 640 * 24576 * 2B = 31457280

typedef __attribute__((ext_vector_type(8))) short  short8v;
typedef __attribute__((ext_vector_type(4))) float  float4v;
typedef __attribute__((ext_vector_type(4))) int    int4v;

// pair enumerations:
// full region (j<=7): for j in 0..7: for i in 0..j   (36 pairs)
__host__ __device__ constexpr int PJF(int p) { int j = 0; while (p >= j + 1) { p -= j + 1; ++j; } return j; }
__host__ __device__ constexpr int PIF(int p) { int j = 0; while (p >= j + 1) { p -= j + 1; ++j; } return p; }
// h1 region (j>=8): for j in 8..15: for i in 0..j    (100 pairs)
__host__ __device__ constexpr int PJH(int p) { int j = 8; while (p >= j + 1) { p -= j + 1; ++j; } return j; }
__host__ __device__ constexpr int PIH(int p) { int j = 8; while (p >= j + 1) { p -= j + 1; ++j; } return p; }

__device__ __forceinline__ unsigned int f_to_bf16u(float f) {
  union { float f; unsigned int i; } v; v.f = f;
  unsigned int x = v.i;
  unsigned int r = (x + 0x7fffu + ((x >> 16) & 1u)) >> 16;
  return r & 0xffffu;
}

// ---------------- kernel 0: bucket nodes by element ----------------
__global__ void k_lists(const int* __restrict__ idx, int* __restrict__ ws_offs,
                        int* __restrict__ ws_list) {
  __shared__ int cnt[NEL];
  __shared__ int base[NEL + 1];
  int t = threadIdx.x;
  if (t < NEL) cnt[t] = 0;
  __syncthreads();
  int e = idx[t];
  int pos = atomicAdd(&cnt[e], 1);
  __syncthreads();
  if (t == 0) {
    int a = 0;
    for (int i = 0; i < NEL; ++i) { base[i] = a; a += cnt[i]; }
    base[NEL] = a;
  }
  __syncthreads();
  ws_list[base[e] + pos] = t;
  if (t <= NEL) ws_offs[t] = base[t];
}

// ---------------- kernel 1: pack canonical U rows (bf16) + wallT ----------------
// blocks 0..383: Upack[row][32k], row = o*1536 + u*8 + jj, n = u ^ (o&7).
//   k 0..15 = U3 canonical line * mult({1,3,6}); k 16..23 = U2 * {1,2}; k 24..27 = U1.
// blocks 384..403: wallT[(e*64+c)][32k] = blockdiag(w3,w2,w1) column for channel c.
__global__ __launch_bounds__(256) void k_pack(const float* __restrict__ U3,
                                              const float* __restrict__ U2,
                                              const float* __restrict__ U1,
                                              const float* __restrict__ w3,
                                              const float* __restrict__ w2,
                                              const float* __restrict__ w1,
                                              unsigned short* __restrict__ Upack,
                                              unsigned short* __restrict__ wallT) {
  int b = blockIdx.x;
  int t = threadIdx.x;
  if (b < 384) {
    int tau = b * 256 + t;             // (row, kq): kq = quarter of the 32-k row
    int row = tau >> 2, kq = tau & 3;
    int o = row / 1536;
    int rem = row - o * 1536;
    int u = rem >> 3, jj = rem & 7;
    int n = u ^ (o & 7);               // inverse of the baked swizzle (involution)
    float v[8] = {0.f, 0.f, 0.f, 0.f, 0.f, 0.f, 0.f, 0.f};
    if (n < 172) {                     // cubic rows: k 0..15 live
      int ci, cj, h;
      if (n < 72) { int p = n >> 1; h = n & 1; int j = 0; while (p >= j + 1) { p -= j + 1; ++j; } ci = p; cj = j; }
      else        { int p = n - 72; h = 1;     int j = 8; while (p >= j + 1) { p -= j + 1; ++j; } ci = p; cj = j; }
      int l = h * 8 + jj;
      if (kq < 2 && l >= cj) {
        const float* line = U3 + ((((size_t)o * 16 + ci) * 16 + cj) * 16 + l) * 16 + kq * 8;
        float4 q0 = *(const float4*)line;
        float4 q1 = *(const float4*)(line + 4);
        float mult = (ci == cj) ? (cj == l ? 1.f : 3.f) : (cj == l ? 3.f : 6.f);
        v[0] = q0.x * mult; v[1] = q0.y * mult; v[2] = q0.z * mult; v[3] = q0.w * mult;
        v[4] = q1.x * mult; v[5] = q1.y * mult; v[6] = q1.z * mult; v[7] = q1.w * mult;
      }
    } else {                           // tail rows
      int r = (n - 172) * 8 + jj;
      if (kq == 2 && r < 136) {        // quad: k 16..23
        int p = r, i2 = 0; while (p >= 16 - i2) { p -= 16 - i2; ++i2; }
        int a = i2, bb = i2 + p;
        const float* line = U2 + (((o * 16 + a) * 16) + bb) * 8;
        float4 q0 = *(const float4*)line;
        float4 q1 = *(const float4*)(line + 4);
        float sc = (a == bb) ? 1.f : 2.f;
        v[0] = q0.x * sc; v[1] = q0.y * sc; v[2] = q0.z * sc; v[3] = q0.w * sc;
        v[4] = q1.x * sc; v[5] = q1.y * sc; v[6] = q1.z * sc; v[7] = q1.w * sc;
      } else if (kq == 3 && r >= 136 && r < 152) {  // linear: k 24..27
        int a = r - 136;
        float4 q0 = *(const float4*)(U1 + (o * 16 + a) * 4);
        v[0] = q0.x; v[1] = q0.y; v[2] = q0.z; v[3] = q0.w;
      }
    }
    uint4 st;
    st.x = f_to_bf16u(v[0]) | (f_to_bf16u(v[1]) << 16);
    st.y = f_to_bf16u(v[2]) | (f_to_bf16u(v[3]) << 16);
    st.z = f_to_bf16u(v[4]) | (f_to_bf16u(v[5]) << 16);
    st.w = f_to_bf16u(v[6]) | (f_to_bf16u(v[7]) << 16);
    *(uint4*)(Upack + (size_t)row * 32 + kq * 8) = st;
  } else {
    int tau = (b - 384) * 256 + t;     // 5120 threads: (ecw, 4-k group)
    if (tau < 5120) {
      int kg = tau & 7, ecw = tau >> 3;
      int e = ecw >> 6, c = ecw & 63;
      unsigned int pk[2];
#pragma unroll
      for (int hh = 0; hh < 2; ++hh) {
        unsigned int lo = 0, hi = 0;
        int k0 = kg * 4 + hh * 2;
        float f0 = 0.f, f1 = 0.f;
        int k = k0;
        f0 = (k < 16) ? w3[(e * 16 + k) * NCH + c]
           : (k < 24) ? w2[(e * 8 + (k - 16)) * NCH + c]
           : (k < 28) ? w1[(e * 4 + (k - 24)) * NCH + c] : 0.f;
        k = k0 + 1;
        f1 = (k < 16) ? w3[(e * 16 + k) * NCH + c]
           : (k < 24) ? w2[(e * 8 + (k - 16)) * NCH + c]
           : (k < 28) ? w1[(e * 4 + (k - 24)) * NCH + c] : 0.f;
        lo = f_to_bf16u(f0); hi = f_to_bf16u(f1);
        pk[hh] = lo | (hi << 16);
      }
      uint2 st = {pk[0], pk[1]};
      *(uint2*)(wallT + (size_t)ecw * 32 + kg * 4) = st;
    }
  }
}

// ---------------- kernel 2: W = Upack x wallT via MFMA ----------------
// grid 960: e = b/96, rb = b%96; wave w = c-tile (c = w*16+rc); 16 row-tiles/block.
// A-frag: Upack rows (coalesced 1KB/wave); B-frag: wallT row (hoisted);
// D rows g*4+reg are consecutive -> pack 4 bf16, 8B store per lane.
__global__ __launch_bounds__(256) void k_bgemm(const unsigned short* __restrict__ Upack,
                                               const unsigned short* __restrict__ wallT,
                                               unsigned short* __restrict__ W) {
  int b = blockIdx.x;
  int e = b / 96, rb = b - e * 96;
  int t = threadIdx.x, w = t >> 6, lane = t & 63;
  int rc = lane & 15, g = lane >> 4;
  int c = w * 16 + rc;
  short8v bv = *(const short8v*)(wallT + ((size_t)(e * 64 + c)) * 32 + g * 8);
  unsigned short* Wbase = W + ((size_t)(e * 64 + c)) * NROWS;
#pragma unroll 4
  for (int rt = 0; rt < 16; ++rt) {
    int row0 = (rb * 16 + rt) * 16;
    short8v av = *(const short8v*)(Upack + (size_t)(row0 + rc) * 32 + g * 8);
    float4v acc = {0.f, 0.f, 0.f, 0.f};
    acc = __builtin_amdgcn_mfma_f32_16x16x32_bf16(av, bv, acc, 0, 0, 0);
    unsigned int lo, hi;
    asm("v_cvt_pk_bf16_f32 %0, %1, %2" : "=v"(lo) : "v"(acc[0]), "v"(acc[1]));
    asm("v_cvt_pk_bf16_f32 %0, %1, %2" : "=v"(hi) : "v"(acc[2]), "v"(acc[3]));
    uint2 st = {lo, hi};
    *(uint2*)(Wbase + row0 + g * 4) = st;
  }
}

// ---------------- kernel 3: MFMA main (W staged in LDS once per block) ----------------
#define PACK_MFMA(M0, M1, M2, M3, M4, M5, M6, M7, KK, ACC) { \
  int b0, b1, b2, b3; \
  asm("v_cvt_pk_bf16_f32 %0, %1, %2" : "=v"(b0) : "v"(M0), "v"(M1)); \
  asm("v_cvt_pk_bf16_f32 %0, %1, %2" : "=v"(b1) : "v"(M2), "v"(M3)); \
  asm("v_cvt_pk_bf16_f32 %0, %1, %2" : "=v"(b2) : "v"(M4), "v"(M5)); \
  asm("v_cvt_pk_bf16_f32 %0, %1, %2" : "=v"(b3) : "v"(M6), "v"(M7)); \
  int4v ai = {b0, b1, b2, b3}; \
  short8v av = __builtin_bit_cast(short8v, ai); \
  short8v bv = *(const short8v*)(((KK) & 1 ? bpO : bpE) + ((KK) >> 1) * 128); \
  ACC = __builtin_amdgcn_mfma_f32_16x16x32_bf16(av, bv, ACC, 0, 0, 0); \
}

#define FULL_STEP(KK, ACC) { \
  constexpr int iA = PIF(2 * (KK)), jA = PJF(2 * (KK)); \
  constexpr int iB = PIF(2 * (KK) + 1), jB = PJF(2 * (KK) + 1); \
  float xxA = xr[iA] * xr[jA]; \
  float xxB = xr[iB] * xr[jB]; \
  float xx = selOdd ? xxB : xxA; \
  PACK_MFMA(xx * xsF[0], xx * xsF[1], xx * xsF[2], xx * xsF[3], \
            xx * xsF[4], xx * xsF[5], xx * xsF[6], xx * xsF[7], KK, ACC) \
}

#define H1_STEP(KK, ACC) { \
  constexpr int q = 4 * ((KK) - 18); \
  constexpr int i0 = PIH(q), j0 = PJH(q); \
  constexpr int i1 = PIH(q + 1), j1 = PJH(q + 1); \
  constexpr int i2 = PIH(q + 2), j2 = PJH(q + 2); \
  constexpr int i3 = PIH(q + 3), j3 = PJH(q + 3); \
  float xx0 = xr[i0] * xr[j0], xx1 = xr[i1] * xr[j1]; \
  float xx2 = xr[i2] * xr[j2], xx3 = xr[i3] * xr[j3]; \
  float xxE = selG1 ? xx1 : xx0; \
  float xxO = selG1 ? xx3 : xx2; \
  float xx = selOdd ? xxO : xxE; \
  PACK_MFMA(xx * xr[8], xx * xr[9], xx * xr[10], xx * xr[11], \
            xx * xr[12], xx * xr[13], xx * xr[14], xx * xr[15], KK, ACC) \
}

#define TAIL_STEP(KK, ACC) { \
  float mv[8]; \
  _Pragma("unroll") \
  for (int jj = 0; jj < 8; ++jj) { \
    int spec = sT[((KK) - 43) * 32 + g * 8 + jj]; \
    mv[jj] = sXw[spec & 31] * sXw[(spec >> 8) & 31]; \
  } \
  PACK_MFMA(mv[0], mv[1], mv[2], mv[3], mv[4], mv[5], mv[6], mv[7], KK, ACC) \
}

__global__ __launch_bounds__(512, 4) void k_main(const float* __restrict__ x,
                                                 const int* __restrict__ offs,
                                                 const int* __restrict__ list,
                                                 const unsigned short* __restrict__ W,
                                                 float* __restrict__ out) {
  __shared__ unsigned short sB[16 * NCHUNK * 8];   // 49152 B, producer-swizzled W[ec]
  __shared__ float sX[8][16][18];
  __shared__ int sT[160];
  int t = threadIdx.x;
  int w = t >> 6, lane = t & 63;
  int rc = lane & 15;
  int g = lane >> 4;
  bool selOdd = g >= 2;
  bool selG1 = g & 1;

  int ec = blockIdx.x;                 // block b -> XCD b%8 == ec%8
  int e = ec >> 6, c = ec & 63;

  // stage W[ec] -> LDS (reg-staged, linear; swizzle already baked by producer)
  {
    const uint4* Wg4 = (const uint4*)(W + (size_t)ec * NROWS);
    uint4* sB4 = (uint4*)sB;
#pragma unroll
    for (int s = 0; s < 6; ++s) sB4[t + 512 * s] = Wg4[t + 512 * s];
  }
  if (t < 160) {
    int r = t, a, b;
    if (r < 136) { int p = r, i2 = 0; while (p >= 16 - i2) { p -= 16 - i2; ++i2; } a = i2; b = i2 + p; }
    else if (r < 152) { a = r - 136; b = 16; }
    else { a = 17; b = 17; }
    sT[r] = a | (b << 8);
  }
  __syncthreads();

  float* sXw = &sX[w][rc][0];
  int off = offs[e], nb = offs[e + 1] - off;
  int nt = (nb + 15) >> 4;
  // swizzled per-lane B bases: unit = rc*192 + (KK>>1)*8 + 4*((KK&1)^r2) + (g^(rc&3))
  int r2 = (rc >> 2) & 1;
  const char* bpE = (const char*)sB + rc * 3072 + ((g ^ (rc & 3)) + 4 * r2) * 16;
  const char* bpO = (const char*)sB + rc * 3072 + ((g ^ (rc & 3)) + 4 * (1 ^ r2)) * 16;

  for (int tile = w; tile < nt; tile += 8) {
    int m = tile * 16 + rc;
    int node = list[off + (m < nb ? m : nb - 1)];
    float xr[16];
    {
      const float4* xp = (const float4*)(x + ((size_t)node * NCH + c) * 16);
      float4 q0 = xp[0], q1 = xp[1], q2 = xp[2], q3 = xp[3];
      xr[0] = q0.x; xr[1] = q0.y; xr[2] = q0.z; xr[3] = q0.w;
      xr[4] = q1.x; xr[5] = q1.y; xr[6] = q1.z; xr[7] = q1.w;
      xr[8] = q2.x; xr[9] = q2.y; xr[10] = q2.z; xr[11] = q2.w;
      xr[12] = q3.x; xr[13] = q3.y; xr[14] = q3.z; xr[15] = q3.w;
    }
    float xsF[8];
#pragma unroll
    for (int j = 0; j < 8; ++j) xsF[j] = selG1 ? xr[8 + j] : xr[j];
    if (g == 0) {                      // publish row for tail steps (same-wave use only)
#pragma unroll
      for (int l = 0; l < 16; ++l) sXw[l] = xr[l];
      sXw[16] = 1.f; sXw[17] = 0.f;
    }

    float4v acc0 = {0.f, 0.f, 0.f, 0.f};
    float4v acc1 = {0.f, 0.f, 0.f, 0.f};
#define S2F(K) FULL_STEP(K, acc0) FULL_STEP((K) + 1, acc1)
#define S2H(K) H1_STEP(K, acc0) H1_STEP((K) + 1, acc1)
    S2F(0) S2F(2) S2F(4) S2F(6) S2F(8) S2F(10) S2F(12) S2F(14) S2F(16)
    S2H(18) S2H(20) S2H(22) S2H(24) S2H(26) S2H(28) S2H(30) S2H(32)
    S2H(34) S2H(36) S2H(38) S2H(40)
    H1_STEP(42, acc0)
    TAIL_STEP(43, acc1)
    TAIL_STEP(44, acc0) TAIL_STEP(45, acc1)
    TAIL_STEP(46, acc0) TAIL_STEP(47, acc1)
    float4v accs = acc0 + acc1;

#pragma unroll
    for (int r3 = 0; r3 < 4; ++r3) {
      int row = g * 4 + r3;
      int mrow = tile * 16 + row;
      if (mrow < nb) {
        int nd = __shfl(node, row);
        out[((size_t)nd * NCH + c) * 16 + rc] = accs[r3];
      }
    }
  }
}

extern "C" void kernel_launch(void* const* d_in, const int* in_sizes, int n_in,
                              void* d_out, int out_size, void* d_ws, size_t ws_size,
                              hipStream_t stream) {
  (void)in_sizes; (void)n_in; (void)out_size; (void)ws_size;
  const float* x   = (const float*)d_in[0];
  const int*   idx = (const int*)d_in[1];
  const float* w1  = (const float*)d_in[2];
  const float* w2  = (const float*)d_in[3];
  const float* w3  = (const float*)d_in[4];
  const float* U1  = (const float*)d_in[5];
  const float* U2  = (const float*)d_in[6];
  const float* U3  = (const float*)d_in[7];
  float* out = (float*)d_out;
  char* ws = (char*)d_ws;
  int* ws_offs = (int*)(ws + WS_OFFS);
  int* ws_list = (int*)(ws + WS_LIST);
  unsigned short* wallT = (unsigned short*)(ws + WS_WALLT);
  unsigned short* Upack = (unsigned short*)(ws + WS_UPACK);
  unsigned short* W     = (unsigned short*)(ws + WS_W);

  hipLaunchKernelGGL(k_lists, dim3(1), dim3(1024), 0, stream, idx, ws_offs, ws_list);
  hipLaunchKernelGGL(k_pack, dim3(404), dim3(256), 0, stream, U3, U2, U1, w3, w2, w1,
                     Upack, wallT);
  hipLaunchKernelGGL(k_bgemm, dim3(960), dim3(256), 0, stream, Upack, wallT, W);
  hipLaunchKernelGGL(k_main, dim3(640), dim3(512), 0, stream, x, ws_offs, ws_list, W, out);
}

// Round 7
// 44.509 us; speedup vs baseline: 1.6883x; 1.2017x over previous
//
#include <hip/hip_runtime.h>
#include <hip/hip_bf16.h>

#define NCH 64
#define NEL 10
// Basis: 172 cubic chunks (72 full-pair j<=7, 100 h1-only j>=8) + 20 tail chunks = 192 chunks
// = 48 MFMA K-steps of 32. Table layout: W[ec][o][chunk-unit u][8 j] bf16, where the
// 16B chunk n of row o is stored at unit u = n ^ (o&7)  (XOR swizzle, baked at build).
#define NCHUNK 192
#define NSTEP 48
#define NROWS 24576          // 16 o * 192 units * 8 jj  (= per-ec W row count)

#define WS_OFFS   0
#define WS_LIST   1024
#define WS_WALLT  8192       // 640 * 32 * 2B = 40960
#define WS_UPACK  65536      // 24576 * 32 * 2B = 1572864
#define WS_W      2097152    // 640 * 24576 * 2B = 31457280

typedef __attribute__((ext_vector_type(8))) short  short8v;
typedef __attribute__((ext_vector_type(4))) float  float4v;
typedef __attribute__((ext_vector_type(4))) int    int4v;

// pair enumerations:
// full region (j<=7): for j in 0..7: for i in 0..j   (36 pairs)
__host__ __device__ constexpr int PJF(int p) { int j = 0; while (p >= j + 1) { p -= j + 1; ++j; } return j; }
__host__ __device__ constexpr int PIF(int p) { int j = 0; while (p >= j + 1) { p -= j + 1; ++j; } return p; }
// h1 region (j>=8): for j in 8..15: for i in 0..j    (100 pairs)
__host__ __device__ constexpr int PJH(int p) { int j = 8; while (p >= j + 1) { p -= j + 1; ++j; } return j; }
__host__ __device__ constexpr int PIH(int p) { int j = 8; while (p >= j + 1) { p -= j + 1; ++j; } return p; }

__device__ __forceinline__ unsigned int f_to_bf16u(float f) {
  union { float f; unsigned int i; } v; v.f = f;
  unsigned int x = v.i;
  unsigned int r = (x + 0x7fffu + ((x >> 16) & 1u)) >> 16;
  return r & 0xffffu;
}

// ---------------- kernel 1: pack canonical U rows (bf16) + wallT + node lists ----------------
// blocks 0..383: Upack[row][32k], row = o*1536 + u*8 + jj, n = u ^ (o&7).
//   k 0..15 = U3 canonical line * mult({1,3,6}); k 16..23 = U2 * {1,2}; k 24..27 = U1.
// blocks 384..403: wallT[(e*64+c)][32k] = blockdiag(w3,w2,w1) column for channel c.
// block 404: bucket nodes by element (was k_lists).
__global__ __launch_bounds__(256) void k_pack(const float* __restrict__ U3,
                                              const float* __restrict__ U2,
                                              const float* __restrict__ U1,
                                              const float* __restrict__ w3,
                                              const float* __restrict__ w2,
                                              const float* __restrict__ w1,
                                              const int* __restrict__ idx,
                                              unsigned short* __restrict__ Upack,
                                              unsigned short* __restrict__ wallT,
                                              int* __restrict__ ws_offs,
                                              int* __restrict__ ws_list) {
  int b = blockIdx.x;
  int t = threadIdx.x;
  if (b == 404) {                      // node bucketing: 256 threads x 4 nodes
    __shared__ int cnt[NEL];
    __shared__ int base[NEL + 1];
    if (t < NEL) cnt[t] = 0;
    __syncthreads();
    int mye[4], myp[4];
#pragma unroll
    for (int k = 0; k < 4; ++k) {
      int n = t + k * 256;
      int e = idx[n];
      mye[k] = e;
      myp[k] = atomicAdd(&cnt[e], 1);
    }
    __syncthreads();
    if (t == 0) {
      int a = 0;
      for (int i = 0; i < NEL; ++i) { base[i] = a; a += cnt[i]; }
      base[NEL] = a;
    }
    __syncthreads();
#pragma unroll
    for (int k = 0; k < 4; ++k) ws_list[base[mye[k]] + myp[k]] = t + k * 256;
    if (t <= NEL) ws_offs[t] = base[t];
  } else if (b < 384) {
    int tau = b * 256 + t;             // (row, kq): kq = quarter of the 32-k row
    int row = tau >> 2, kq = tau & 3;
    int o = row / 1536;
    int rem = row - o * 1536;
    int u = rem >> 3, jj = rem & 7;
    int n = u ^ (o & 7);               // inverse of the baked swizzle (involution)
    float v[8] = {0.f, 0.f, 0.f, 0.f, 0.f, 0.f, 0.f, 0.f};
    if (n < 172) {                     // cubic rows: k 0..15 live
      int ci, cj, h;
      if (n < 72) { int p = n >> 1; h = n & 1; int j = 0; while (p >= j + 1) { p -= j + 1; ++j; } ci = p; cj = j; }
      else        { int p = n - 72; h = 1;     int j = 8; while (p >= j + 1) { p -= j + 1; ++j; } ci = p; cj = j; }
      int l = h * 8 + jj;
      if (kq < 2 && l >= cj) {
        const float* line = U3 + ((((size_t)o * 16 + ci) * 16 + cj) * 16 + l) * 16 + kq * 8;
        float4 q0 = *(const float4*)line;
        float4 q1 = *(const float4*)(line + 4);
        float mult = (ci == cj) ? (cj == l ? 1.f : 3.f) : (cj == l ? 3.f : 6.f);
        v[0] = q0.x * mult; v[1] = q0.y * mult; v[2] = q0.z * mult; v[3] = q0.w * mult;
        v[4] = q1.x * mult; v[5] = q1.y * mult; v[6] = q1.z * mult; v[7] = q1.w * mult;
      }
    } else {                           // tail rows
      int r = (n - 172) * 8 + jj;
      if (kq == 2 && r < 136) {        // quad: k 16..23
        int p = r, i2 = 0; while (p >= 16 - i2) { p -= 16 - i2; ++i2; }
        int a = i2, bb = i2 + p;
        const float* line = U2 + (((o * 16 + a) * 16) + bb) * 8;
        float4 q0 = *(const float4*)line;
        float4 q1 = *(const float4*)(line + 4);
        float sc = (a == bb) ? 1.f : 2.f;
        v[0] = q0.x * sc; v[1] = q0.y * sc; v[2] = q0.z * sc; v[3] = q0.w * sc;
        v[4] = q1.x * sc; v[5] = q1.y * sc; v[6] = q1.z * sc; v[7] = q1.w * sc;
      } else if (kq == 3 && r >= 136 && r < 152) {  // linear: k 24..27
        int a = r - 136;
        float4 q0 = *(const float4*)(U1 + (o * 16 + a) * 4);
        v[0] = q0.x; v[1] = q0.y; v[2] = q0.z; v[3] = q0.w;
      }
    }
    uint4 st;
    st.x = f_to_bf16u(v[0]) | (f_to_bf16u(v[1]) << 16);
    st.y = f_to_bf16u(v[2]) | (f_to_bf16u(v[3]) << 16);
    st.z = f_to_bf16u(v[4]) | (f_to_bf16u(v[5]) << 16);
    st.w = f_to_bf16u(v[6]) | (f_to_bf16u(v[7]) << 16);
    *(uint4*)(Upack + (size_t)row * 32 + kq * 8) = st;
  } else {
    int tau = (b - 384) * 256 + t;     // 5120 threads: (ecw, 4-k group)
    if (tau < 5120) {
      int kg = tau & 7, ecw = tau >> 3;
      int e = ecw >> 6, c = ecw & 63;
      unsigned int pk[2];
#pragma unroll
      for (int hh = 0; hh < 2; ++hh) {
        int k0 = kg * 4 + hh * 2;
        float f0, f1;
        int k = k0;
        f0 = (k < 16) ? w3[(e * 16 + k) * NCH + c]
           : (k < 24) ? w2[(e * 8 + (k - 16)) * NCH + c]
           : (k < 28) ? w1[(e * 4 + (k - 24)) * NCH + c] : 0.f;
        k = k0 + 1;
        f1 = (k < 16) ? w3[(e * 16 + k) * NCH + c]
           : (k < 24) ? w2[(e * 8 + (k - 16)) * NCH + c]
           : (k < 28) ? w1[(e * 4 + (k - 24)) * NCH + c] : 0.f;
        pk[hh] = f_to_bf16u(f0) | (f_to_bf16u(f1) << 16);
      }
      uint2 st = {pk[0], pk[1]};
      *(uint2*)(wallT + (size_t)ecw * 32 + kg * 4) = st;
    }
  }
}

// ---------------- kernel 2: W = Upack x wallT via MFMA, LDS-transposed stores ----------------
// grid 960: e = b/96, rb = b%96 (256 rows); wave w = c-tile (c = w*16+rc).
// Per wave: 4 groups x {4 MFMA row-tiles -> cvt_pk -> ds_write_b64 (swizzled 2KB
// per-wave region) -> ds_read_b128 -> 2x global_store_dwordx4}. Store pattern:
// 16 c-segments x 64 B contiguous per instruction (vs 64 x 8 B scatter before).
__global__ __launch_bounds__(256) void k_bgemm(const unsigned short* __restrict__ Upack,
                                               const unsigned short* __restrict__ wallT,
                                               unsigned short* __restrict__ W) {
  __shared__ char sLT[4][2048];        // per-wave transpose buffers (no barrier needed)
  int b = blockIdx.x;
  int e = b / 96, rb = b - e * 96;
  int t = threadIdx.x, w = t >> 6, lane = t & 63;
  int rc = lane & 15, g = lane >> 4;
  int c = w * 16 + rc;
  short8v bv = *(const short8v*)(wallT + ((size_t)(e * 64 + c)) * 32 + g * 8);
  char* wb = &sLT[w][0];
  int c_r = lane >> 2, q = lane & 3;
  int woff = rc * 128 + ((g * 8) ^ ((rc & 7) << 4));        // + rt2*32 per tile
  int roff0 = c_r * 128 + ((q * 16) ^ ((c_r & 7) << 4));
  int roff1 = c_r * 128 + (((64 + q * 16)) ^ ((c_r & 7) << 4));
  unsigned short* gcol = W + ((size_t)(e * 64 + w * 16 + c_r)) * NROWS + rb * 256;

#pragma unroll 1
  for (int grp = 0; grp < 4; ++grp) {
#pragma unroll
    for (int rt2 = 0; rt2 < 4; ++rt2) {
      int row0 = (rb * 16 + grp * 4 + rt2) * 16;
      short8v av = *(const short8v*)(Upack + (size_t)(row0 + rc) * 32 + g * 8);
      float4v acc = {0.f, 0.f, 0.f, 0.f};
      acc = __builtin_amdgcn_mfma_f32_16x16x32_bf16(av, bv, acc, 0, 0, 0);
      unsigned int lo, hi;
      asm("v_cvt_pk_bf16_f32 %0, %1, %2" : "=v"(lo) : "v"(acc[0]), "v"(acc[1]));
      asm("v_cvt_pk_bf16_f32 %0, %1, %2" : "=v"(hi) : "v"(acc[2]), "v"(acc[3]));
      uint2 pk = {lo, hi};             // rows g*4..g*4+3 of tile rt2, column c
      *(uint2*)(wb + (woff ^ (rt2 * 32))) = pk;   // rt2*32 has bits 5-6: XOR == add here
    }
    // per-wave LDS dependency: compiler inserts lgkmcnt before these reads
    uint4 u0 = *(const uint4*)(wb + roff0);
    uint4 u1 = *(const uint4*)(wb + roff1);
    unsigned short* gp = gcol + grp * 64;
    *(uint4*)(gp + q * 8) = u0;        // rows grp*64 + q*8..+7      (64B x 16 c segs)
    *(uint4*)(gp + 32 + q * 8) = u1;   // rows grp*64 + 32 + q*8..+7
  }
}

// ---------------- kernel 3: MFMA main (W staged in LDS once per block) ----------------
#define PACK_MFMA(M0, M1, M2, M3, M4, M5, M6, M7, KK, ACC) { \
  int b0, b1, b2, b3; \
  asm("v_cvt_pk_bf16_f32 %0, %1, %2" : "=v"(b0) : "v"(M0), "v"(M1)); \
  asm("v_cvt_pk_bf16_f32 %0, %1, %2" : "=v"(b1) : "v"(M2), "v"(M3)); \
  asm("v_cvt_pk_bf16_f32 %0, %1, %2" : "=v"(b2) : "v"(M4), "v"(M5)); \
  asm("v_cvt_pk_bf16_f32 %0, %1, %2" : "=v"(b3) : "v"(M6), "v"(M7)); \
  int4v ai = {b0, b1, b2, b3}; \
  short8v av = __builtin_bit_cast(short8v, ai); \
  short8v bv = *(const short8v*)(((KK) & 1 ? bpO : bpE) + ((KK) >> 1) * 128); \
  ACC = __builtin_amdgcn_mfma_f32_16x16x32_bf16(av, bv, ACC, 0, 0, 0); \
}

#define FULL_STEP(KK, ACC) { \
  constexpr int iA = PIF(2 * (KK)), jA = PJF(2 * (KK)); \
  constexpr int iB = PIF(2 * (KK) + 1), jB = PJF(2 * (KK) + 1); \
  float xxA = xr[iA] * xr[jA]; \
  float xxB = xr[iB] * xr[jB]; \
  float xx = selOdd ? xxB : xxA; \
  PACK_MFMA(xx * xsF[0], xx * xsF[1], xx * xsF[2], xx * xsF[3], \
            xx * xsF[4], xx * xsF[5], xx * xsF[6], xx * xsF[7], KK, ACC) \
}

#define H1_STEP(KK, ACC) { \
  constexpr int q = 4 * ((KK) - 18); \
  constexpr int i0 = PIH(q), j0 = PJH(q); \
  constexpr int i1 = PIH(q + 1), j1 = PJH(q + 1); \
  constexpr int i2 = PIH(q + 2), j2 = PJH(q + 2); \
  constexpr int i3 = PIH(q + 3), j3 = PJH(q + 3); \
  float xx0 = xr[i0] * xr[j0], xx1 = xr[i1] * xr[j1]; \
  float xx2 = xr[i2] * xr[j2], xx3 = xr[i3] * xr[j3]; \
  float xxE = selG1 ? xx1 : xx0; \
  float xxO = selG1 ? xx3 : xx2; \
  float xx = selOdd ? xxO : xxE; \
  PACK_MFMA(xx * xr[8], xx * xr[9], xx * xr[10], xx * xr[11], \
            xx * xr[12], xx * xr[13], xx * xr[14], xx * xr[15], KK, ACC) \
}

#define TAIL_STEP(KK, ACC) { \
  float mv[8]; \
  _Pragma("unroll") \
  for (int jj = 0; jj < 8; ++jj) { \
    int spec = sT[((KK) - 43) * 32 + g * 8 + jj]; \
    mv[jj] = sXw[spec & 31] * sXw[(spec >> 8) & 31]; \
  } \
  PACK_MFMA(mv[0], mv[1], mv[2], mv[3], mv[4], mv[5], mv[6], mv[7], KK, ACC) \
}

__global__ __launch_bounds__(512, 4) void k_main(const float* __restrict__ x,
                                                 const int* __restrict__ offs,
                                                 const int* __restrict__ list,
                                                 const unsigned short* __restrict__ W,
                                                 float* __restrict__ out) {
  __shared__ unsigned short sB[16 * NCHUNK * 8];   // 49152 B, producer-swizzled W[ec]
  __shared__ float sX[8][16][18];
  __shared__ int sT[160];
  int t = threadIdx.x;
  int w = t >> 6, lane = t & 63;
  int rc = lane & 15;
  int g = lane >> 4;
  bool selOdd = g >= 2;
  bool selG1 = g & 1;

  int ec = blockIdx.x;                 // block b -> XCD b%8 == ec%8
  int e = ec >> 6, c = ec & 63;

  // stage W[ec] -> LDS (reg-staged, linear; swizzle already baked by producer)
  {
    const uint4* Wg4 = (const uint4*)(W + (size_t)ec * NROWS);
    uint4* sB4 = (uint4*)sB;
#pragma unroll
    for (int s = 0; s < 6; ++s) sB4[t + 512 * s] = Wg4[t + 512 * s];
  }
  if (t < 160) {
    int r = t, a, b;
    if (r < 136) { int p = r, i2 = 0; while (p >= 16 - i2) { p -= 16 - i2; ++i2; } a = i2; b = i2 + p; }
    else if (r < 152) { a = r - 136; b = 16; }
    else { a = 17; b = 17; }
    sT[r] = a | (b << 8);
  }
  __syncthreads();

  float* sXw = &sX[w][rc][0];
  int off = offs[e], nb = offs[e + 1] - off;
  int nt = (nb + 15) >> 4;
  // swizzled per-lane B bases: unit = rc*192 + (KK>>1)*8 + 4*((KK&1)^r2) + (g^(rc&3))
  int r2 = (rc >> 2) & 1;
  const char* bpE = (const char*)sB + rc * 3072 + ((g ^ (rc & 3)) + 4 * r2) * 16;
  const char* bpO = (const char*)sB + rc * 3072 + ((g ^ (rc & 3)) + 4 * (1 ^ r2)) * 16;

  for (int tile = w; tile < nt; tile += 8) {
    int m = tile * 16 + rc;
    int node = list[off + (m < nb ? m : nb - 1)];
    float xr[16];
    {
      const float4* xp = (const float4*)(x + ((size_t)node * NCH + c) * 16);
      float4 q0 = xp[0], q1 = xp[1], q2 = xp[2], q3 = xp[3];
      xr[0] = q0.x; xr[1] = q0.y; xr[2] = q0.z; xr[3] = q0.w;
      xr[4] = q1.x; xr[5] = q1.y; xr[6] = q1.z; xr[7] = q1.w;
      xr[8] = q2.x; xr[9] = q2.y; xr[10] = q2.z; xr[11] = q2.w;
      xr[12] = q3.x; xr[13] = q3.y; xr[14] = q3.z; xr[15] = q3.w;
    }
    float xsF[8];
#pragma unroll
    for (int j = 0; j < 8; ++j) xsF[j] = selG1 ? xr[8 + j] : xr[j];
    if (g == 0) {                      // publish row for tail steps (same-wave use only)
#pragma unroll
      for (int l = 0; l < 16; ++l) sXw[l] = xr[l];
      sXw[16] = 1.f; sXw[17] = 0.f;
    }

    float4v acc0 = {0.f, 0.f, 0.f, 0.f};
    float4v acc1 = {0.f, 0.f, 0.f, 0.f};
#define S2F(K) FULL_STEP(K, acc0) FULL_STEP((K) + 1, acc1)
#define S2H(K) H1_STEP(K, acc0) H1_STEP((K) + 1, acc1)
    S2F(0) S2F(2) S2F(4) S2F(6) S2F(8) S2F(10) S2F(12) S2F(14) S2F(16)
    S2H(18) S2H(20) S2H(22) S2H(24) S2H(26) S2H(28) S2H(30) S2H(32)
    S2H(34) S2H(36) S2H(38) S2H(40)
    H1_STEP(42, acc0)
    TAIL_STEP(43, acc1)
    TAIL_STEP(44, acc0) TAIL_STEP(45, acc1)
    TAIL_STEP(46, acc0) TAIL_STEP(47, acc1)
    float4v accs = acc0 + acc1;

#pragma unroll
    for (int r3 = 0; r3 < 4; ++r3) {
      int row = g * 4 + r3;
      int mrow = tile * 16 + row;
      if (mrow < nb) {
        int nd = __shfl(node, row);
        out[((size_t)nd * NCH + c) * 16 + rc] = accs[r3];
      }
    }
  }
}

extern "C" void kernel_launch(void* const* d_in, const int* in_sizes, int n_in,
                              void* d_out, int out_size, void* d_ws, size_t ws_size,
                              hipStream_t stream) {
  (void)in_sizes; (void)n_in; (void)out_size; (void)ws_size;
  const float* x   = (const float*)d_in[0];
  const int*   idx = (const int*)d_in[1];
  const float* w1  = (const float*)d_in[2];
  const float* w2  = (const float*)d_in[3];
  const float* w3  = (const float*)d_in[4];
  const float* U1  = (const float*)d_in[5];
  const float* U2  = (const float*)d_in[6];
  const float* U3  = (const float*)d_in[7];
  float* out = (float*)d_out;
  char* ws = (char*)d_ws;
  int* ws_offs = (int*)(ws + WS_OFFS);
  int* ws_list = (int*)(ws + WS_LIST);
  unsigned short* wallT = (unsigned short*)(ws + WS_WALLT);
  unsigned short* Upack = (unsigned short*)(ws + WS_UPACK);
  unsigned short* W     = (unsigned short*)(ws + WS_W);

  hipLaunchKernelGGL(k_pack, dim3(405), dim3(256), 0, stream, U3, U2, U1, w3, w2, w1,
                     idx, Upack, wallT, ws_offs, ws_list);
  hipLaunchKernelGGL(k_bgemm, dim3(960), dim3(256), 0, stream, Upack, wallT, W);
  hipLaunchKernelGGL(k_main, dim3(640), dim3(512), 0, stream, x, ws_offs, ws_list, W, out);
}

// Round 8
// 41.552 us; speedup vs baseline: 1.8085x; 1.0712x over previous
//
#include <hip/hip_runtime.h>
#include <hip/hip_bf16.h>

#define NCH 64
#define NEL 10
// Basis: 172 cubic chunks (72 full-pair j<=7, 100 h1-only j>=8) + 20 tail chunks = 192 chunks
// = 48 MFMA K-steps of 32. Table layout: W[ec][o][chunk-unit u][8 j] bf16, where the
// 16B chunk n of row o is stored at unit u = n ^ (o&7)  (XOR swizzle, baked at build).
#define NCHUNK 192
#define NSTEP 48
#define NROWS 24576          // 16 o * 192 units * 8 jj  (= per-ec W row count)

#define WS_OFFS   0
#define WS_LIST   1024
#define WS_W      2097152    // 640 * 24576 * 2B = 31457280

typedef __attribute__((ext_vector_type(8))) short  short8v;
typedef __attribute__((ext_vector_type(4))) float  float4v;
typedef __attribute__((ext_vector_type(4))) int    int4v;

// pair enumerations:
// full region (j<=7): for j in 0..7: for i in 0..j   (36 pairs)
__host__ __device__ constexpr int PJF(int p) { int j = 0; while (p >= j + 1) { p -= j + 1; ++j; } return j; }
__host__ __device__ constexpr int PIF(int p) { int j = 0; while (p >= j + 1) { p -= j + 1; ++j; } return p; }
// h1 region (j>=8): for j in 8..15: for i in 0..j    (100 pairs)
__host__ __device__ constexpr int PJH(int p) { int j = 8; while (p >= j + 1) { p -= j + 1; ++j; } return j; }
__host__ __device__ constexpr int PIH(int p) { int j = 8; while (p >= j + 1) { p -= j + 1; ++j; } return p; }

__device__ __forceinline__ unsigned int f_to_bf16u(float f) {
  union { float f; unsigned int i; } v; v.f = f;
  unsigned int x = v.i;
  unsigned int r = (x + 0x7fffu + ((x >> 16) & 1u)) >> 16;
  return r & 0xffffu;
}

// ---- kernel 1: fused pack + GEMM: W rows rb*256..+255 for element e ----
// grid 961: blocks 0..959: e = b/96, rb = b%96. block 960: node bucketing.
// Phase 1: pack 256 canonical U rows (bf16, swizzle baked) -> sU (16KB LDS);
//          wallT slice for e -> sWt (4KB). Bit-identical values to the old k_pack.
// Phase 2: MFMA (A from sU, B from sWt) + per-wave LDS-transposed coalesced stores.
__global__ __launch_bounds__(256) void k_bgemm(const float* __restrict__ U3,
                                               const float* __restrict__ U2,
                                               const float* __restrict__ U1,
                                               const float* __restrict__ w3,
                                               const float* __restrict__ w2,
                                               const float* __restrict__ w1,
                                               const int* __restrict__ idx,
                                               unsigned short* __restrict__ W,
                                               int* __restrict__ ws_offs,
                                               int* __restrict__ ws_list) {
  __shared__ unsigned short sU[256 * 32];   // 16384 B: packed A rows (local row = t)
  __shared__ unsigned short sWt[64 * 32];   // 4096 B: wallT[c][k] for this e
  __shared__ char sLT[4][2048];             // per-wave transpose buffers
  __shared__ int cnt[NEL];
  __shared__ int base[NEL + 1];
  int b = blockIdx.x;
  int t = threadIdx.x;

  if (b == 960) {                      // node bucketing: 256 threads x 4 nodes
    if (t < NEL) cnt[t] = 0;
    __syncthreads();
    int mye[4], myp[4];
#pragma unroll
    for (int k = 0; k < 4; ++k) {
      int n = t + k * 256;
      int e = idx[n];
      mye[k] = e;
      myp[k] = atomicAdd(&cnt[e], 1);
    }
    __syncthreads();
    if (t == 0) {
      int a = 0;
      for (int i = 0; i < NEL; ++i) { base[i] = a; a += cnt[i]; }
      base[NEL] = a;
    }
    __syncthreads();
#pragma unroll
    for (int k = 0; k < 4; ++k) ws_list[base[mye[k]] + myp[k]] = t + k * 256;
    if (t <= NEL) ws_offs[t] = base[t];
    return;
  }

  int e = b / 96, rb = b - e * 96;

  // ---- phase 1: pack this block's 256 A rows into sU ----
  {
    int row = rb * 256 + t;
    int o = row / 1536;
    int rem = row - o * 1536;
    int u = rem >> 3, jj = rem & 7;
    int n = u ^ (o & 7);               // inverse of the baked swizzle (involution)
#pragma unroll
    for (int kq = 0; kq < 4; ++kq) {
      float v[8] = {0.f, 0.f, 0.f, 0.f, 0.f, 0.f, 0.f, 0.f};
      if (n < 172) {                   // cubic rows: k 0..15 live
        int ci, cj, h;
        if (n < 72) { int p = n >> 1; h = n & 1; int j = 0; while (p >= j + 1) { p -= j + 1; ++j; } ci = p; cj = j; }
        else        { int p = n - 72; h = 1;     int j = 8; while (p >= j + 1) { p -= j + 1; ++j; } ci = p; cj = j; }
        int l = h * 8 + jj;
        if (kq < 2 && l >= cj) {
          const float* line = U3 + ((((size_t)o * 16 + ci) * 16 + cj) * 16 + l) * 16 + kq * 8;
          float4 q0 = *(const float4*)line;
          float4 q1 = *(const float4*)(line + 4);
          float mult = (ci == cj) ? (cj == l ? 1.f : 3.f) : (cj == l ? 3.f : 6.f);
          v[0] = q0.x * mult; v[1] = q0.y * mult; v[2] = q0.z * mult; v[3] = q0.w * mult;
          v[4] = q1.x * mult; v[5] = q1.y * mult; v[6] = q1.z * mult; v[7] = q1.w * mult;
        }
      } else {                         // tail rows
        int r = (n - 172) * 8 + jj;
        if (kq == 2 && r < 136) {      // quad: k 16..23
          int p = r, i2 = 0; while (p >= 16 - i2) { p -= 16 - i2; ++i2; }
          int a = i2, bb = i2 + p;
          const float* line = U2 + (((o * 16 + a) * 16) + bb) * 8;
          float4 q0 = *(const float4*)line;
          float4 q1 = *(const float4*)(line + 4);
          float sc = (a == bb) ? 1.f : 2.f;
          v[0] = q0.x * sc; v[1] = q0.y * sc; v[2] = q0.z * sc; v[3] = q0.w * sc;
          v[4] = q1.x * sc; v[5] = q1.y * sc; v[6] = q1.z * sc; v[7] = q1.w * sc;
        } else if (kq == 3 && r >= 136 && r < 152) {  // linear: k 24..27
          int a = r - 136;
          float4 q0 = *(const float4*)(U1 + (o * 16 + a) * 4);
          v[0] = q0.x; v[1] = q0.y; v[2] = q0.z; v[3] = q0.w;
        }
      }
      uint4 st;
      st.x = f_to_bf16u(v[0]) | (f_to_bf16u(v[1]) << 16);
      st.y = f_to_bf16u(v[2]) | (f_to_bf16u(v[3]) << 16);
      st.z = f_to_bf16u(v[4]) | (f_to_bf16u(v[5]) << 16);
      st.w = f_to_bf16u(v[6]) | (f_to_bf16u(v[7]) << 16);
      *(uint4*)(&sU[t * 32 + kq * 8]) = st;
    }
  }
  // ---- phase 1b: wallT slice for this e ----
  {
    int c = t & 63, kg = t >> 6;       // kg 0..3, 8 k each
    unsigned int pk[4];
#pragma unroll
    for (int hh = 0; hh < 4; ++hh) {
      int k0 = kg * 8 + hh * 2;
      float f0, f1;
      int k = k0;
      f0 = (k < 16) ? w3[(e * 16 + k) * NCH + c]
         : (k < 24) ? w2[(e * 8 + (k - 16)) * NCH + c]
         : (k < 28) ? w1[(e * 4 + (k - 24)) * NCH + c] : 0.f;
      k = k0 + 1;
      f1 = (k < 16) ? w3[(e * 16 + k) * NCH + c]
         : (k < 24) ? w2[(e * 8 + (k - 16)) * NCH + c]
         : (k < 28) ? w1[(e * 4 + (k - 24)) * NCH + c] : 0.f;
      pk[hh] = f_to_bf16u(f0) | (f_to_bf16u(f1) << 16);
    }
    uint4 st = {pk[0], pk[1], pk[2], pk[3]};
    *(uint4*)(&sWt[c * 32 + kg * 8]) = st;
  }
  __syncthreads();

  // ---- phase 2: GEMM + transposed coalesced stores (unchanged logic) ----
  int w = t >> 6, lane = t & 63;
  int rc = lane & 15, g = lane >> 4;
  int c = w * 16 + rc;
  short8v bv = *(const short8v*)(sWt + c * 32 + g * 8);
  char* wb = &sLT[w][0];
  int c_r = lane >> 2, q = lane & 3;
  int woff = rc * 128 + ((g * 8) ^ ((rc & 7) << 4));        // + rt2*32 per tile
  int roff0 = c_r * 128 + ((q * 16) ^ ((c_r & 7) << 4));
  int roff1 = c_r * 128 + (((64 + q * 16)) ^ ((c_r & 7) << 4));
  unsigned short* gcol = W + ((size_t)(e * 64 + w * 16 + c_r)) * NROWS + rb * 256;

#pragma unroll 1
  for (int grp = 0; grp < 4; ++grp) {
#pragma unroll
    for (int rt2 = 0; rt2 < 4; ++rt2) {
      int rowL = (grp * 4 + rt2) * 16 + rc;
      short8v av = *(const short8v*)(sU + rowL * 32 + g * 8);
      float4v acc = {0.f, 0.f, 0.f, 0.f};
      acc = __builtin_amdgcn_mfma_f32_16x16x32_bf16(av, bv, acc, 0, 0, 0);
      unsigned int lo, hi;
      asm("v_cvt_pk_bf16_f32 %0, %1, %2" : "=v"(lo) : "v"(acc[0]), "v"(acc[1]));
      asm("v_cvt_pk_bf16_f32 %0, %1, %2" : "=v"(hi) : "v"(acc[2]), "v"(acc[3]));
      uint2 pk = {lo, hi};             // rows g*4..g*4+3 of tile rt2, column c
      *(uint2*)(wb + (woff ^ (rt2 * 32))) = pk;
    }
    uint4 u0 = *(const uint4*)(wb + roff0);
    uint4 u1 = *(const uint4*)(wb + roff1);
    unsigned short* gp = gcol + grp * 64;
    *(uint4*)(gp + q * 8) = u0;        // rows grp*64 + q*8..+7      (64B x 16 c segs)
    *(uint4*)(gp + 32 + q * 8) = u1;   // rows grp*64 + 32 + q*8..+7
  }
}

// ---------------- kernel 2: MFMA main (W staged in LDS once per block) ----------------
#define PACK_MFMA(M0, M1, M2, M3, M4, M5, M6, M7, KK, ACC) { \
  int b0, b1, b2, b3; \
  asm("v_cvt_pk_bf16_f32 %0, %1, %2" : "=v"(b0) : "v"(M0), "v"(M1)); \
  asm("v_cvt_pk_bf16_f32 %0, %1, %2" : "=v"(b1) : "v"(M2), "v"(M3)); \
  asm("v_cvt_pk_bf16_f32 %0, %1, %2" : "=v"(b2) : "v"(M4), "v"(M5)); \
  asm("v_cvt_pk_bf16_f32 %0, %1, %2" : "=v"(b3) : "v"(M6), "v"(M7)); \
  int4v ai = {b0, b1, b2, b3}; \
  short8v av = __builtin_bit_cast(short8v, ai); \
  short8v bv = *(const short8v*)(((KK) & 1 ? bpO : bpE) + ((KK) >> 1) * 128); \
  ACC = __builtin_amdgcn_mfma_f32_16x16x32_bf16(av, bv, ACC, 0, 0, 0); \
}

#define FULL_STEP(KK, ACC) { \
  constexpr int iA = PIF(2 * (KK)), jA = PJF(2 * (KK)); \
  constexpr int iB = PIF(2 * (KK) + 1), jB = PJF(2 * (KK) + 1); \
  float xxA = xr[iA] * xr[jA]; \
  float xxB = xr[iB] * xr[jB]; \
  float xx = selOdd ? xxB : xxA; \
  PACK_MFMA(xx * xsF[0], xx * xsF[1], xx * xsF[2], xx * xsF[3], \
            xx * xsF[4], xx * xsF[5], xx * xsF[6], xx * xsF[7], KK, ACC) \
}

#define H1_STEP(KK, ACC) { \
  constexpr int q = 4 * ((KK) - 18); \
  constexpr int i0 = PIH(q), j0 = PJH(q); \
  constexpr int i1 = PIH(q + 1), j1 = PJH(q + 1); \
  constexpr int i2 = PIH(q + 2), j2 = PJH(q + 2); \
  constexpr int i3 = PIH(q + 3), j3 = PJH(q + 3); \
  float xx0 = xr[i0] * xr[j0], xx1 = xr[i1] * xr[j1]; \
  float xx2 = xr[i2] * xr[j2], xx3 = xr[i3] * xr[j3]; \
  float xxE = selG1 ? xx1 : xx0; \
  float xxO = selG1 ? xx3 : xx2; \
  float xx = selOdd ? xxO : xxE; \
  PACK_MFMA(xx * xr[8], xx * xr[9], xx * xr[10], xx * xr[11], \
            xx * xr[12], xx * xr[13], xx * xr[14], xx * xr[15], KK, ACC) \
}

#define TAIL_STEP(KK, ACC) { \
  float mv[8]; \
  _Pragma("unroll") \
  for (int jj = 0; jj < 8; ++jj) { \
    int spec = sT[((KK) - 43) * 32 + g * 8 + jj]; \
    mv[jj] = sXw[spec & 31] * sXw[(spec >> 8) & 31]; \
  } \
  PACK_MFMA(mv[0], mv[1], mv[2], mv[3], mv[4], mv[5], mv[6], mv[7], KK, ACC) \
}

__global__ __launch_bounds__(512, 4) void k_main(const float* __restrict__ x,
                                                 const int* __restrict__ offs,
                                                 const int* __restrict__ list,
                                                 const unsigned short* __restrict__ W,
                                                 float* __restrict__ out) {
  __shared__ unsigned short sB[16 * NCHUNK * 8];   // 49152 B, producer-swizzled W[ec]
  __shared__ float sX[8][16][18];
  __shared__ int sT[160];
  int t = threadIdx.x;
  int w = t >> 6, lane = t & 63;
  int rc = lane & 15;
  int g = lane >> 4;
  bool selOdd = g >= 2;
  bool selG1 = g & 1;

  int ec = blockIdx.x;                 // block b -> XCD b%8 == ec%8
  int e = ec >> 6, c = ec & 63;

  // stage W[ec] -> LDS (reg-staged, linear; swizzle already baked by producer)
  {
    const uint4* Wg4 = (const uint4*)(W + (size_t)ec * NROWS);
    uint4* sB4 = (uint4*)sB;
#pragma unroll
    for (int s = 0; s < 6; ++s) sB4[t + 512 * s] = Wg4[t + 512 * s];
  }
  if (t < 160) {
    int r = t, a, b;
    if (r < 136) { int p = r, i2 = 0; while (p >= 16 - i2) { p -= 16 - i2; ++i2; } a = i2; b = i2 + p; }
    else if (r < 152) { a = r - 136; b = 16; }
    else { a = 17; b = 17; }
    sT[r] = a | (b << 8);
  }
  __syncthreads();

  float* sXw = &sX[w][rc][0];
  int off = offs[e], nb = offs[e + 1] - off;
  int nt = (nb + 15) >> 4;
  // swizzled per-lane B bases: unit = rc*192 + (KK>>1)*8 + 4*((KK&1)^r2) + (g^(rc&3))
  int r2 = (rc >> 2) & 1;
  const char* bpE = (const char*)sB + rc * 3072 + ((g ^ (rc & 3)) + 4 * r2) * 16;
  const char* bpO = (const char*)sB + rc * 3072 + ((g ^ (rc & 3)) + 4 * (1 ^ r2)) * 16;

  for (int tile = w; tile < nt; tile += 8) {
    int m = tile * 16 + rc;
    int node = list[off + (m < nb ? m : nb - 1)];
    float xr[16];
    {
      const float4* xp = (const float4*)(x + ((size_t)node * NCH + c) * 16);
      float4 q0 = xp[0], q1 = xp[1], q2 = xp[2], q3 = xp[3];
      xr[0] = q0.x; xr[1] = q0.y; xr[2] = q0.z; xr[3] = q0.w;
      xr[4] = q1.x; xr[5] = q1.y; xr[6] = q1.z; xr[7] = q1.w;
      xr[8] = q2.x; xr[9] = q2.y; xr[10] = q2.z; xr[11] = q2.w;
      xr[12] = q3.x; xr[13] = q3.y; xr[14] = q3.z; xr[15] = q3.w;
    }
    float xsF[8];
#pragma unroll
    for (int j = 0; j < 8; ++j) xsF[j] = selG1 ? xr[8 + j] : xr[j];
    if (g == 0) {                      // publish row for tail steps (same-wave use only)
#pragma unroll
      for (int l = 0; l < 16; ++l) sXw[l] = xr[l];
      sXw[16] = 1.f; sXw[17] = 0.f;
    }

    float4v acc0 = {0.f, 0.f, 0.f, 0.f};
    float4v acc1 = {0.f, 0.f, 0.f, 0.f};
#define S2F(K) FULL_STEP(K, acc0) FULL_STEP((K) + 1, acc1)
#define S2H(K) H1_STEP(K, acc0) H1_STEP((K) + 1, acc1)
    S2F(0) S2F(2) S2F(4) S2F(6) S2F(8) S2F(10) S2F(12) S2F(14) S2F(16)
    S2H(18) S2H(20) S2H(22) S2H(24) S2H(26) S2H(28) S2H(30) S2H(32)
    S2H(34) S2H(36) S2H(38) S2H(40)
    H1_STEP(42, acc0)
    TAIL_STEP(43, acc1)
    TAIL_STEP(44, acc0) TAIL_STEP(45, acc1)
    TAIL_STEP(46, acc0) TAIL_STEP(47, acc1)
    float4v accs = acc0 + acc1;

#pragma unroll
    for (int r3 = 0; r3 < 4; ++r3) {
      int row = g * 4 + r3;
      int mrow = tile * 16 + row;
      if (mrow < nb) {
        int nd = __shfl(node, row);
        out[((size_t)nd * NCH + c) * 16 + rc] = accs[r3];
      }
    }
  }
}

extern "C" void kernel_launch(void* const* d_in, const int* in_sizes, int n_in,
                              void* d_out, int out_size, void* d_ws, size_t ws_size,
                              hipStream_t stream) {
  (void)in_sizes; (void)n_in; (void)out_size; (void)ws_size;
  const float* x   = (const float*)d_in[0];
  const int*   idx = (const int*)d_in[1];
  const float* w1  = (const float*)d_in[2];
  const float* w2  = (const float*)d_in[3];
  const float* w3  = (const float*)d_in[4];
  const float* U1  = (const float*)d_in[5];
  const float* U2  = (const float*)d_in[6];
  const float* U3  = (const float*)d_in[7];
  float* out = (float*)d_out;
  char* ws = (char*)d_ws;
  int* ws_offs = (int*)(ws + WS_OFFS);
  int* ws_list = (int*)(ws + WS_LIST);
  unsigned short* W = (unsigned short*)(ws + WS_W);

  hipLaunchKernelGGL(k_bgemm, dim3(961), dim3(256), 0, stream, U3, U2, U1, w3, w2, w1,
                     idx, W, ws_offs, ws_list);
  hipLaunchKernelGGL(k_main, dim3(640), dim3(512), 0, stream, x, ws_offs, ws_list, W, out);
}